// Round 7
// baseline (300.435 us; speedup 1.0000x reference)
//
#include <hip/hip_runtime.h>
#include <hip/hip_cooperative_groups.h>
#include <hip/hip_bf16.h>

namespace cg = cooperative_groups;

// HyperbolicMessagePassing: N=50000, E=600000, D=128.
// out = expmap0( MLP2( mean_scatter( MLP1(logmap0(x))[src] -> dst ) ) )
// R7: single cooperative kernel, 3 phases split by grid.sync():
//  P0: pack W (bf16 MFMA B-frags) + zero degv
//  PA: unified queue {1172 edge-fill chunks (512 e, 2/thread)} + {1563 MLP1 tiles}
//  PB: 1563 tiles of padded-CSR gather+mean + MLP2 + expmap0
// Removes k_init dispatch + 2 launch gaps + fill-after-MLP dispatch tail.

#define DD 128
#define CAP 32  // padded-CSR slots/node; deg~Poisson(12), P(>32)~1e-7

typedef __attribute__((ext_vector_type(8))) short short8;
typedef __attribute__((ext_vector_type(4))) float f32x4;

__device__ __forceinline__ unsigned short f2bf(float f) {
  unsigned u = __float_as_uint(f);
  u += 0x7fffu + ((u >> 16) & 1u);  // round-to-nearest-even
  return (unsigned short)(u >> 16);
}
__device__ __forceinline__ float bf2f(short h) {
  return __uint_as_float(((unsigned)(unsigned short)h) << 16);
}

// ---- MLP1 tile: logmap0 + 2-layer MLP -> node_msg (bf16). 32 rows. ----
__device__ __forceinline__ void mlp1_tile(
    int t, const float* __restrict__ x, const unsigned short* __restrict__ Pa,
    const float* __restrict__ ba, const unsigned short* __restrict__ Pb,
    const float* __restrict__ bb, unsigned short* __restrict__ node_msg, int N,
    unsigned short* As) {
  const int tid = threadIdx.x;
  const int lane = tid & 63;
  const int wv = tid >> 6;  // 0..3
  const int rt = wv >> 1;
  const int ct = wv & 1;
  const int q = lane >> 4;
  const int n15 = lane & 15;
  const int row0 = t * 32;
  const int g = (wv << 2) | q;  // staging group 0..15

#pragma unroll
  for (int i = 0; i < 2; ++i) {
    const int r = g * 2 + i;
    const int grow = row0 + r;
    f32x4 s0 = {0.f, 0.f, 0.f, 0.f}, s1 = {0.f, 0.f, 0.f, 0.f};
    if (grow < N) {
      const f32x4* p = (const f32x4*)(x + (size_t)grow * DD + n15 * 8);
      s0 = p[0];
      s1 = p[1];
      float ss = s0[0]*s0[0] + s0[1]*s0[1] + s0[2]*s0[2] + s0[3]*s0[3]
               + s1[0]*s1[0] + s1[1]*s1[1] + s1[2]*s1[2] + s1[3]*s1[3];
      ss += __shfl_xor(ss, 1);
      ss += __shfl_xor(ss, 2);
      ss += __shfl_xor(ss, 4);
      ss += __shfl_xor(ss, 8);
      float nrm = sqrtf(ss);
      float nc = fminf(fmaxf(nrm, 1e-8f), 1.0f - 1e-5f);
      float sc = atanhf(nc) / nc;
      s0 *= sc;
      s1 *= sc;
    }
    uint4 pk;
    pk.x = (unsigned)f2bf(s0[0]) | ((unsigned)f2bf(s0[1]) << 16);
    pk.y = (unsigned)f2bf(s0[2]) | ((unsigned)f2bf(s0[3]) << 16);
    pk.z = (unsigned)f2bf(s1[0]) | ((unsigned)f2bf(s1[1]) << 16);
    pk.w = (unsigned)f2bf(s1[2]) | ((unsigned)f2bf(s1[3]) << 16);
    *(uint4*)((unsigned*)As + r * 68 + n15 * 4) = pk;
  }
  __syncthreads();

  float bc[4];
#pragma unroll
  for (int c = 0; c < 4; ++c) bc[c] = ba[ct * 64 + c * 16 + n15];
  f32x4 acc[4];
#pragma unroll
  for (int c = 0; c < 4; ++c) acc[c] = (f32x4){0.f, 0.f, 0.f, 0.f};
  const int abase = (rt * 16 + n15) * 136 + q * 8;
#pragma unroll
  for (int s = 0; s < 4; ++s) {
    short8 a = *(const short8*)&As[abase + s * 32];
#pragma unroll
    for (int c = 0; c < 4; ++c) {
      short8 b = *(const short8*)&Pa[(size_t)(((((ct << 2) | c) << 2) | s) * 64 + lane) * 8];
      acc[c] = __builtin_amdgcn_mfma_f32_16x16x32_bf16(a, b, acc[c], 0, 0, 0);
    }
  }
  __syncthreads();

#pragma unroll
  for (int c = 0; c < 4; ++c)
#pragma unroll
    for (int rr = 0; rr < 4; ++rr) {
      float v = fmaxf(acc[c][rr] + bc[c], 0.f);
      As[(rt * 16 + q * 4 + rr) * 136 + ct * 64 + c * 16 + n15] = f2bf(v);
    }
  __syncthreads();

#pragma unroll
  for (int c = 0; c < 4; ++c) bc[c] = bb[ct * 64 + c * 16 + n15];
#pragma unroll
  for (int c = 0; c < 4; ++c) acc[c] = (f32x4){0.f, 0.f, 0.f, 0.f};
#pragma unroll
  for (int s = 0; s < 4; ++s) {
    short8 a = *(const short8*)&As[abase + s * 32];
#pragma unroll
    for (int c = 0; c < 4; ++c) {
      short8 b = *(const short8*)&Pb[(size_t)(((((ct << 2) | c) << 2) | s) * 64 + lane) * 8];
      acc[c] = __builtin_amdgcn_mfma_f32_16x16x32_bf16(a, b, acc[c], 0, 0, 0);
    }
  }

  __syncthreads();
#pragma unroll
  for (int c = 0; c < 4; ++c)
#pragma unroll
    for (int rr = 0; rr < 4; ++rr)
      As[(rt * 16 + q * 4 + rr) * 136 + ct * 64 + c * 16 + n15] =
          f2bf(acc[c][rr] + bc[c]);
  __syncthreads();
#pragma unroll
  for (int k = 0; k < 2; ++k) {
    int u = tid + k * 256;
    int r = u >> 4, ch = u & 15;
    int grow = row0 + r;
    if (grow < N)
      *(short8*)(node_msg + (size_t)grow * DD + ch * 8) =
          *(const short8*)&As[r * 136 + ch * 8];
  }
  __syncthreads();  // protect As reuse across grid-stride iterations
}

// ---- stage2 tile: gather+mean + MLP2 + expmap0 -> out (f32). 32 rows. ----
__device__ __forceinline__ void stage2_tile(
    int t, const unsigned short* __restrict__ node_msg,
    const int* __restrict__ degv, const int* __restrict__ ebuf,
    const unsigned short* __restrict__ Pa, const float* __restrict__ ba,
    const unsigned short* __restrict__ Pb, const float* __restrict__ bb,
    float* __restrict__ out, int N, unsigned short* As, float* nrmb) {
  const int tid = threadIdx.x;
  const int lane = tid & 63;
  const int wv = tid >> 6;
  const int rt = wv >> 1;
  const int ct = wv & 1;
  const int q = lane >> 4;
  const int n15 = lane & 15;
  const int row0 = t * 32;
  const int g = (wv << 2) | q;

#pragma unroll
  for (int i = 0; i < 2; ++i) {
    const int r = g * 2 + i;
    const int grow = row0 + r;
    f32x4 s0 = {0.f, 0.f, 0.f, 0.f}, s1 = {0.f, 0.f, 0.f, 0.f};
    if (grow < N) {
      const int d = degv[grow];
      const int dl = (d < CAP) ? d : CAP;
      const int* eb = ebuf + (size_t)grow * CAP;
      f32x4 t0 = {0.f, 0.f, 0.f, 0.f}, t1 = {0.f, 0.f, 0.f, 0.f};
      int tt = 0;
      for (; tt + 7 < dl; tt += 8) {
        int4 ia = *(const int4*)(eb + tt);
        int4 ib = *(const int4*)(eb + tt + 4);
        short8 v0 = *(const short8*)(node_msg + (size_t)ia.x * DD + n15 * 8);
        short8 v1 = *(const short8*)(node_msg + (size_t)ia.y * DD + n15 * 8);
        short8 v2 = *(const short8*)(node_msg + (size_t)ia.z * DD + n15 * 8);
        short8 v3 = *(const short8*)(node_msg + (size_t)ia.w * DD + n15 * 8);
        short8 v4 = *(const short8*)(node_msg + (size_t)ib.x * DD + n15 * 8);
        short8 v5 = *(const short8*)(node_msg + (size_t)ib.y * DD + n15 * 8);
        short8 v6 = *(const short8*)(node_msg + (size_t)ib.z * DD + n15 * 8);
        short8 v7 = *(const short8*)(node_msg + (size_t)ib.w * DD + n15 * 8);
#pragma unroll
        for (int j = 0; j < 4; ++j) {
          s0[j] += bf2f(v0[j]) + bf2f(v1[j]);
          s1[j] += bf2f(v0[j + 4]) + bf2f(v1[j + 4]);
          t0[j] += bf2f(v2[j]) + bf2f(v3[j]);
          t1[j] += bf2f(v2[j + 4]) + bf2f(v3[j + 4]);
          s0[j] += bf2f(v4[j]) + bf2f(v5[j]);
          s1[j] += bf2f(v4[j + 4]) + bf2f(v5[j + 4]);
          t0[j] += bf2f(v6[j]) + bf2f(v7[j]);
          t1[j] += bf2f(v6[j + 4]) + bf2f(v7[j + 4]);
        }
      }
      if (tt + 3 < dl) {
        int4 ia = *(const int4*)(eb + tt);
        short8 v0 = *(const short8*)(node_msg + (size_t)ia.x * DD + n15 * 8);
        short8 v1 = *(const short8*)(node_msg + (size_t)ia.y * DD + n15 * 8);
        short8 v2 = *(const short8*)(node_msg + (size_t)ia.z * DD + n15 * 8);
        short8 v3 = *(const short8*)(node_msg + (size_t)ia.w * DD + n15 * 8);
#pragma unroll
        for (int j = 0; j < 4; ++j) {
          s0[j] += bf2f(v0[j]) + bf2f(v1[j]);
          s1[j] += bf2f(v0[j + 4]) + bf2f(v1[j + 4]);
          t0[j] += bf2f(v2[j]) + bf2f(v3[j]);
          t1[j] += bf2f(v2[j + 4]) + bf2f(v3[j + 4]);
        }
        tt += 4;
      }
      for (; tt < dl; ++tt) {
        int sa = eb[tt];
        short8 va = *(const short8*)(node_msg + (size_t)sa * DD + n15 * 8);
#pragma unroll
        for (int j = 0; j < 4; ++j) {
          s0[j] += bf2f(va[j]);
          s1[j] += bf2f(va[j + 4]);
        }
      }
      s0 += t0;
      s1 += t1;
      float inv = 1.f / ((float)d + 1e-8f);
      s0 *= inv;
      s1 *= inv;
    }
    uint4 pk;
    pk.x = (unsigned)f2bf(s0[0]) | ((unsigned)f2bf(s0[1]) << 16);
    pk.y = (unsigned)f2bf(s0[2]) | ((unsigned)f2bf(s0[3]) << 16);
    pk.z = (unsigned)f2bf(s1[0]) | ((unsigned)f2bf(s1[1]) << 16);
    pk.w = (unsigned)f2bf(s1[2]) | ((unsigned)f2bf(s1[3]) << 16);
    *(uint4*)((unsigned*)As + r * 68 + n15 * 4) = pk;
  }
  __syncthreads();

  float bc[4];
#pragma unroll
  for (int c = 0; c < 4; ++c) bc[c] = ba[ct * 64 + c * 16 + n15];
  f32x4 acc[4];
#pragma unroll
  for (int c = 0; c < 4; ++c) acc[c] = (f32x4){0.f, 0.f, 0.f, 0.f};
  const int abase = (rt * 16 + n15) * 136 + q * 8;
#pragma unroll
  for (int s = 0; s < 4; ++s) {
    short8 a = *(const short8*)&As[abase + s * 32];
#pragma unroll
    for (int c = 0; c < 4; ++c) {
      short8 b = *(const short8*)&Pa[(size_t)(((((ct << 2) | c) << 2) | s) * 64 + lane) * 8];
      acc[c] = __builtin_amdgcn_mfma_f32_16x16x32_bf16(a, b, acc[c], 0, 0, 0);
    }
  }
  __syncthreads();

#pragma unroll
  for (int c = 0; c < 4; ++c)
#pragma unroll
    for (int rr = 0; rr < 4; ++rr) {
      float v = fmaxf(acc[c][rr] + bc[c], 0.f);
      As[(rt * 16 + q * 4 + rr) * 136 + ct * 64 + c * 16 + n15] = f2bf(v);
    }
  __syncthreads();

#pragma unroll
  for (int c = 0; c < 4; ++c) bc[c] = bb[ct * 64 + c * 16 + n15];
#pragma unroll
  for (int c = 0; c < 4; ++c) acc[c] = (f32x4){0.f, 0.f, 0.f, 0.f};
#pragma unroll
  for (int s = 0; s < 4; ++s) {
    short8 a = *(const short8*)&As[abase + s * 32];
#pragma unroll
    for (int c = 0; c < 4; ++c) {
      short8 b = *(const short8*)&Pb[(size_t)(((((ct << 2) | c) << 2) | s) * 64 + lane) * 8];
      acc[c] = __builtin_amdgcn_mfma_f32_16x16x32_bf16(a, b, acc[c], 0, 0, 0);
    }
  }

  float v[4][4];
#pragma unroll
  for (int rr = 0; rr < 4; ++rr) {
    float ssq = 0.f;
#pragma unroll
    for (int c = 0; c < 4; ++c) {
      v[c][rr] = acc[c][rr] + bc[c];
      ssq += v[c][rr] * v[c][rr];
    }
    ssq += __shfl_xor(ssq, 1);
    ssq += __shfl_xor(ssq, 2);
    ssq += __shfl_xor(ssq, 4);
    ssq += __shfl_xor(ssq, 8);
    if (n15 == 0) nrmb[(rt * 16 + q * 4 + rr) * 2 + ct] = ssq;
  }
  __syncthreads();
#pragma unroll
  for (int rr = 0; rr < 4; ++rr) {
    int r = rt * 16 + q * 4 + rr;
    int grow = row0 + r;
    float ssq = nrmb[r * 2] + nrmb[r * 2 + 1];
    float nrm = sqrtf(ssq);
    float nc = fmaxf(nrm, 1e-8f);
    float sc = tanhf(nc) / nc;
    if (grow < N) {
#pragma unroll
      for (int c = 0; c < 4; ++c)
        out[(size_t)grow * DD + ct * 64 + c * 16 + n15] = v[c][rr] * sc;
    }
  }
  __syncthreads();  // protect As/nrmb reuse across grid-stride iterations
}

__global__ __launch_bounds__(256) void k_mega(
    const float* __restrict__ x, const int* __restrict__ ei,
    const float* __restrict__ w1, const float* __restrict__ w2,
    const float* __restrict__ w3, const float* __restrict__ w4,
    const float* __restrict__ b1, const float* __restrict__ b2,
    const float* __restrict__ b3, const float* __restrict__ b4,
    unsigned short* __restrict__ P, int* __restrict__ degv,
    int* __restrict__ ebuf, unsigned short* __restrict__ node_msg,
    float* __restrict__ out, int N, int E, int nfill, int nmlp) {
  __shared__ unsigned short As[32 * 136];
  __shared__ float nrmb[64];
  cg::grid_group grid = cg::this_grid();
  const int tid = threadIdx.x;
  const int bid = blockIdx.x;
  const int gsz = gridDim.x;

  // ---- Phase 0: pack W (32 units) + zero degv ----
  const int nzero = (N + 255) >> 8;
  for (int u = bid; u < 32 + nzero; u += gsz) {
    if (u < 32) {
      int idx = u * 256 + tid;
      int m = idx >> 11, id = idx & 2047;
      int f = id >> 6, l = id & 63;
      int cc = f >> 2, s = f & 3, q = l >> 4, n15 = l & 15;
      const float* W = (m == 0) ? w1 : (m == 1) ? w2 : (m == 2) ? w3 : w4;
      const float* wp = W + (s * 32 + q * 8) * DD + cc * 16 + n15;
      unsigned short* op = P + (size_t)m * 16384 + (size_t)id * 8;
#pragma unroll
      for (int j = 0; j < 8; ++j) op[j] = f2bf(wp[j * DD]);
    } else {
      int i = (u - 32) * 256 + tid;
      if (i < N) degv[i] = 0;
    }
  }
  grid.sync();

  // ---- Phase A: edge-fill chunks (512 edges, 2/thread) + MLP1 tiles ----
  for (int u = bid; u < nfill + nmlp; u += gsz) {
    if (u < nfill) {
      int e = u * 512 + tid;
#pragma unroll
      for (int k = 0; k < 2; ++k, e += 256) {
        if (e < E) {
          int dst = ei[e];       // edge_index[0] = row (dst)
          int srcn = ei[E + e];  // edge_index[1] = col (src)
          int pos = atomicAdd(degv + dst, 1);
          if (pos < CAP) ebuf[(size_t)dst * CAP + pos] = srcn;
        }
      }
    } else {
      mlp1_tile(u - nfill, x, P, b1, P + 16384, b2, node_msg, N, As);
    }
  }
  grid.sync();

  // ---- Phase B: gather + MLP2 + expmap0 ----
  for (int u = bid; u < nmlp; u += gsz)
    stage2_tile(u, node_msg, degv, ebuf, P + 2 * 16384, b3, P + 3 * 16384, b4,
                out, N, As, nrmb);
}

extern "C" void kernel_launch(void* const* d_in, const int* in_sizes, int n_in,
                              void* d_out, int out_size, void* d_ws, size_t ws_size,
                              hipStream_t stream) {
  const float* x = (const float*)d_in[0];
  const int* ei = (const int*)d_in[1];
  const float* w1 = (const float*)d_in[2];
  const float* b1 = (const float*)d_in[3];
  const float* w2 = (const float*)d_in[4];
  const float* b2 = (const float*)d_in[5];
  const float* w3 = (const float*)d_in[6];
  const float* b3 = (const float*)d_in[7];
  const float* w4 = (const float*)d_in[8];
  const float* b4 = (const float*)d_in[9];
  int N = in_sizes[0] / DD;
  int E = in_sizes[1] / 2;
  int nfill = (E + 511) / 512;
  int nmlp = (N + 31) / 32;

  // ws carve: node_msg[N*128 bf16] | degv[N] | ebuf[N*32 int] | P[4*16384 bf16]
  unsigned short* node_msg = (unsigned short*)d_ws;
  int* degv = (int*)(node_msg + (size_t)N * DD);
  int* ebuf = degv + N;
  uintptr_t pw = (uintptr_t)(ebuf + (size_t)N * CAP);
  pw = (pw + 63) & ~(uintptr_t)63;
  unsigned short* P = (unsigned short*)pw;
  float* outp = (float*)d_out;

  int occ = 0;
  if (hipOccupancyMaxActiveBlocksPerMultiprocessor(&occ, (const void*)k_mega,
                                                   256, 0) != hipSuccess ||
      occ <= 0)
    occ = 4;
  int grid = occ * 256;  // 256 CUs on MI355X
  if (grid > 2048) grid = 2048;

  void* args[] = {&x,  &ei, &w1, &w2, &w3,   &w4,   &b1,       &b2,
                  &b3, &b4, &P,  &degv, &ebuf, &node_msg, &outp,
                  &N,  &E,  &nfill, &nmlp};
  hipLaunchCooperativeKernel((const void*)k_mega, dim3(grid), dim3(256), args,
                             0, stream);
}

// Round 8
// 169.148 us; speedup vs baseline: 1.7762x; 1.7762x over previous
//
#include <hip/hip_runtime.h>
#include <hip/hip_bf16.h>

// HyperbolicMessagePassing: N=50000, E=600000, D=128.
// out = expmap0( MLP2( mean_scatter( MLP1(logmap0(x))[src] -> dst ) ) )
// Message MLP depends only on src -> compute per-node (50k rows not 600k).
// R8: revert to best-measured R4b structure (3 dispatches, 512-thr, CAP=64,
// 4-deep gather = 170.8us). Adds: 2-edge/thread fill ILP, hoisted deg loads
// in stage2, nontemporal out stores. Mega-kernel (R7) regressed -> abandoned.

#define DD 128
#define CAP 64  // padded-CSR slots per node

typedef __attribute__((ext_vector_type(8))) short short8;
typedef __attribute__((ext_vector_type(4))) float f32x4;

__device__ __forceinline__ unsigned short f2bf(float f) {
  unsigned u = __float_as_uint(f);
  u += 0x7fffu + ((u >> 16) & 1u);  // round-to-nearest-even
  return (unsigned short)(u >> 16);
}
__device__ __forceinline__ float bf2f(short h) {
  return __uint_as_float(((unsigned)(unsigned short)h) << 16);
}

// blocks [0,32): pack 4 W (fp32 128x128) into bf16 MFMA B-frag-linear order:
//   P[m*16384 + ((cc*4+s)*64 + lane)*8 + j]
//     = bf16(W[(s*32+(lane>>4)*8+j)*128 + cc*16+(lane&15)])
// blocks [32,..): zero degv[N]
__global__ void k_init(const float* __restrict__ w1, const float* __restrict__ w2,
                       const float* __restrict__ w3, const float* __restrict__ w4,
                       unsigned short* __restrict__ P, int* __restrict__ degv, int N) {
  if (blockIdx.x < 32) {
    int idx = blockIdx.x * 256 + threadIdx.x;  // 4 matrices x 2048 (frag,lane)
    int m = idx >> 11;
    int id = idx & 2047;
    int f = id >> 6, l = id & 63;
    int cc = f >> 2, s = f & 3, q = l >> 4, n15 = l & 15;
    const float* W = (m == 0) ? w1 : (m == 1) ? w2 : (m == 2) ? w3 : w4;
    const float* wp = W + (s * 32 + q * 8) * DD + cc * 16 + n15;
    unsigned short* op = P + (size_t)m * 16384 + (size_t)id * 8;
#pragma unroll
    for (int j = 0; j < 8; ++j) op[j] = f2bf(wp[j * DD]);
  } else {
    int i = (blockIdx.x - 32) * 256 + threadIdx.x;
    if (i < N) degv[i] = 0;
  }
}

// stage1: blocks [0,nf) = fused logmap0 + 2-layer MLP -> node_msg (bf16);
//         blocks [nf,..) = padded-CSR edge fill, 2 edges/thread (ILP).
// 512 threads = 8 waves. Wave wv: rt=wv>>1 (16 rows), ct=wv&1 (64 cols).
// Staging: 32 groups of 16 lanes, 2 rows each.
__global__ __launch_bounds__(512) void k_stage1(
    const float* __restrict__ x, const int* __restrict__ ei,
    const unsigned short* __restrict__ Pa, const float* __restrict__ ba,
    const unsigned short* __restrict__ Pb, const float* __restrict__ bb,
    unsigned short* __restrict__ node_msg, int* __restrict__ degv,
    int* __restrict__ ebuf, int N, int E, int nf) {
  __shared__ unsigned short As[64 * 136];  // row stride 136 shorts
  const int tid = threadIdx.x;

  if (blockIdx.x >= nf) {  // ---- edge-fill part: 1024 edges/block ----
    int e0 = (blockIdx.x - nf) * 1024 + tid;
    int e1 = e0 + 512;
    int d0 = 0, d1 = 0, s0i = 0, s1i = 0;
    if (e0 < E) { d0 = ei[e0]; s0i = ei[E + e0]; }
    if (e1 < E) { d1 = ei[e1]; s1i = ei[E + e1]; }
    int p0 = 0, p1 = 0;
    if (e0 < E) p0 = atomicAdd(degv + d0, 1);
    if (e1 < E) p1 = atomicAdd(degv + d1, 1);
    if (e0 < E && p0 < CAP) ebuf[(size_t)d0 * CAP + p0] = s0i;
    if (e1 < E && p1 < CAP) ebuf[(size_t)d1 * CAP + p1] = s1i;
    return;
  }

  const int lane = tid & 63;
  const int wv = tid >> 6;  // 0..7
  const int rt = wv >> 1;   // row-tile 0..3
  const int ct = wv & 1;    // col-tile 0..1
  const int q = lane >> 4;
  const int n15 = lane & 15;
  const int row0 = blockIdx.x * 64;
  const int g = (wv << 2) | q;  // staging group 0..31

  // ---- stage A tile: logmap0, group g rows g*2..g*2+1, 16 lanes/row ----
#pragma unroll
  for (int i = 0; i < 2; ++i) {
    const int r = g * 2 + i;
    const int grow = row0 + r;
    f32x4 s0 = {0.f, 0.f, 0.f, 0.f}, s1 = {0.f, 0.f, 0.f, 0.f};
    if (grow < N) {
      const f32x4* p = (const f32x4*)(x + (size_t)grow * DD + n15 * 8);
      s0 = p[0];
      s1 = p[1];
      float ss = s0[0]*s0[0] + s0[1]*s0[1] + s0[2]*s0[2] + s0[3]*s0[3]
               + s1[0]*s1[0] + s1[1]*s1[1] + s1[2]*s1[2] + s1[3]*s1[3];
      ss += __shfl_xor(ss, 1);
      ss += __shfl_xor(ss, 2);
      ss += __shfl_xor(ss, 4);
      ss += __shfl_xor(ss, 8);
      float nrm = sqrtf(ss);
      float nc = fminf(fmaxf(nrm, 1e-8f), 1.0f - 1e-5f);
      float sc = atanhf(nc) / nc;
      s0 *= sc;
      s1 *= sc;
    }
    uint4 pk;
    pk.x = (unsigned)f2bf(s0[0]) | ((unsigned)f2bf(s0[1]) << 16);
    pk.y = (unsigned)f2bf(s0[2]) | ((unsigned)f2bf(s0[3]) << 16);
    pk.z = (unsigned)f2bf(s1[0]) | ((unsigned)f2bf(s1[1]) << 16);
    pk.w = (unsigned)f2bf(s1[2]) | ((unsigned)f2bf(s1[3]) << 16);
    *(uint4*)((unsigned*)As + r * 68 + n15 * 4) = pk;
  }
  __syncthreads();

  // ---- layer 1 ----
  float bc[4];
#pragma unroll
  for (int c = 0; c < 4; ++c) bc[c] = ba[ct * 64 + c * 16 + n15];
  f32x4 acc[4];
#pragma unroll
  for (int c = 0; c < 4; ++c) acc[c] = (f32x4){0.f, 0.f, 0.f, 0.f};
  const int abase = (rt * 16 + n15) * 136 + q * 8;  // A[m=n15][k=q*8+j]
#pragma unroll
  for (int s = 0; s < 4; ++s) {
    short8 a = *(const short8*)&As[abase + s * 32];
#pragma unroll
    for (int c = 0; c < 4; ++c) {
      short8 b = *(const short8*)&Pa[(size_t)(((((ct << 2) | c) << 2) | s) * 64 + lane) * 8];
      acc[c] = __builtin_amdgcn_mfma_f32_16x16x32_bf16(a, b, acc[c], 0, 0, 0);
    }
  }
  __syncthreads();

  // relu + bias -> As (C/D: row = rt*16 + q*4 + rr, col = ct*64 + c*16 + n15)
#pragma unroll
  for (int c = 0; c < 4; ++c)
#pragma unroll
    for (int rr = 0; rr < 4; ++rr) {
      float v = fmaxf(acc[c][rr] + bc[c], 0.f);
      As[(rt * 16 + q * 4 + rr) * 136 + ct * 64 + c * 16 + n15] = f2bf(v);
    }
  __syncthreads();

  // ---- layer 2 ----
#pragma unroll
  for (int c = 0; c < 4; ++c) bc[c] = bb[ct * 64 + c * 16 + n15];
#pragma unroll
  for (int c = 0; c < 4; ++c) acc[c] = (f32x4){0.f, 0.f, 0.f, 0.f};
#pragma unroll
  for (int s = 0; s < 4; ++s) {
    short8 a = *(const short8*)&As[abase + s * 32];
#pragma unroll
    for (int c = 0; c < 4; ++c) {
      short8 b = *(const short8*)&Pb[(size_t)(((((ct << 2) | c) << 2) | s) * 64 + lane) * 8];
      acc[c] = __builtin_amdgcn_mfma_f32_16x16x32_bf16(a, b, acc[c], 0, 0, 0);
    }
  }

  // write bf16 node_msg via LDS repack -> coalesced 16B stores
  __syncthreads();
#pragma unroll
  for (int c = 0; c < 4; ++c)
#pragma unroll
    for (int rr = 0; rr < 4; ++rr)
      As[(rt * 16 + q * 4 + rr) * 136 + ct * 64 + c * 16 + n15] =
          f2bf(acc[c][rr] + bc[c]);
  __syncthreads();
#pragma unroll
  for (int k = 0; k < 2; ++k) {  // 64 rows x 16 chunks = 1024 units / 512 thr
    int u = tid + k * 512;
    int r = u >> 4, ch = u & 15;
    int grow = row0 + r;
    if (grow < N)
      *(short8*)(node_msg + (size_t)grow * DD + ch * 8) =
          *(const short8*)&As[r * 136 + ch * 8];
  }
}

// stage2: padded-CSR gather + mean -> 2-layer MLP -> expmap0 -> out (f32)
__global__ __launch_bounds__(512) void k_stage2(
    const unsigned short* __restrict__ node_msg, const int* __restrict__ degv,
    const int* __restrict__ ebuf, const unsigned short* __restrict__ Pa,
    const float* __restrict__ ba, const unsigned short* __restrict__ Pb,
    const float* __restrict__ bb, float* __restrict__ out, int N) {
  __shared__ unsigned short As[64 * 136];
  __shared__ float nrmb[128];  // [row][ct] partial norms
  const int tid = threadIdx.x;
  const int lane = tid & 63;
  const int wv = tid >> 6;
  const int rt = wv >> 1;
  const int ct = wv & 1;
  const int q = lane >> 4;
  const int n15 = lane & 15;
  const int row0 = blockIdx.x * 64;
  const int g = (wv << 2) | q;

  // hoist deg loads for both of this group's rows (hide row-1 deg latency)
  int dpre[2];
#pragma unroll
  for (int i = 0; i < 2; ++i) {
    int grow = row0 + g * 2 + i;
    dpre[i] = (grow < N) ? degv[grow] : 0;
  }

  // ---- gather + mean: group g rows g*2..g*2+1, 4x unroll ----
#pragma unroll
  for (int i = 0; i < 2; ++i) {
    const int r = g * 2 + i;
    const int grow = row0 + r;
    f32x4 s0 = {0.f, 0.f, 0.f, 0.f}, s1 = {0.f, 0.f, 0.f, 0.f};
    if (grow < N) {
      const int d = dpre[i];
      const int dl = (d < CAP) ? d : CAP;
      const int* eb = ebuf + (size_t)grow * CAP;
      f32x4 t0 = {0.f, 0.f, 0.f, 0.f}, t1 = {0.f, 0.f, 0.f, 0.f};
      int t = 0;
      for (; t + 3 < dl; t += 4) {  // 4 x 16B row loads in flight
        int4 idx = *(const int4*)(eb + t);  // eb 256B-aligned
        short8 v0 = *(const short8*)(node_msg + (size_t)idx.x * DD + n15 * 8);
        short8 v1 = *(const short8*)(node_msg + (size_t)idx.y * DD + n15 * 8);
        short8 v2 = *(const short8*)(node_msg + (size_t)idx.z * DD + n15 * 8);
        short8 v3 = *(const short8*)(node_msg + (size_t)idx.w * DD + n15 * 8);
#pragma unroll
        for (int j = 0; j < 4; ++j) {
          s0[j] += bf2f(v0[j]) + bf2f(v1[j]);
          s1[j] += bf2f(v0[j + 4]) + bf2f(v1[j + 4]);
          t0[j] += bf2f(v2[j]) + bf2f(v3[j]);
          t1[j] += bf2f(v2[j + 4]) + bf2f(v3[j + 4]);
        }
      }
      for (; t < dl; ++t) {
        int sa = eb[t];
        short8 va = *(const short8*)(node_msg + (size_t)sa * DD + n15 * 8);
#pragma unroll
        for (int j = 0; j < 4; ++j) {
          s0[j] += bf2f(va[j]);
          s1[j] += bf2f(va[j + 4]);
        }
      }
      s0 += t0;
      s1 += t1;
      float inv = 1.f / ((float)d + 1e-8f);  // mean (count + EPS)
      s0 *= inv;
      s1 *= inv;
    }
    uint4 pk;
    pk.x = (unsigned)f2bf(s0[0]) | ((unsigned)f2bf(s0[1]) << 16);
    pk.y = (unsigned)f2bf(s0[2]) | ((unsigned)f2bf(s0[3]) << 16);
    pk.z = (unsigned)f2bf(s1[0]) | ((unsigned)f2bf(s1[1]) << 16);
    pk.w = (unsigned)f2bf(s1[2]) | ((unsigned)f2bf(s1[3]) << 16);
    *(uint4*)((unsigned*)As + r * 68 + n15 * 4) = pk;
  }
  __syncthreads();

  // ---- layer 1 ----
  float bc[4];
#pragma unroll
  for (int c = 0; c < 4; ++c) bc[c] = ba[ct * 64 + c * 16 + n15];
  f32x4 acc[4];
#pragma unroll
  for (int c = 0; c < 4; ++c) acc[c] = (f32x4){0.f, 0.f, 0.f, 0.f};
  const int abase = (rt * 16 + n15) * 136 + q * 8;
#pragma unroll
  for (int s = 0; s < 4; ++s) {
    short8 a = *(const short8*)&As[abase + s * 32];
#pragma unroll
    for (int c = 0; c < 4; ++c) {
      short8 b = *(const short8*)&Pa[(size_t)(((((ct << 2) | c) << 2) | s) * 64 + lane) * 8];
      acc[c] = __builtin_amdgcn_mfma_f32_16x16x32_bf16(a, b, acc[c], 0, 0, 0);
    }
  }
  __syncthreads();

#pragma unroll
  for (int c = 0; c < 4; ++c)
#pragma unroll
    for (int rr = 0; rr < 4; ++rr) {
      float v = fmaxf(acc[c][rr] + bc[c], 0.f);
      As[(rt * 16 + q * 4 + rr) * 136 + ct * 64 + c * 16 + n15] = f2bf(v);
    }
  __syncthreads();

  // ---- layer 2 ----
#pragma unroll
  for (int c = 0; c < 4; ++c) bc[c] = bb[ct * 64 + c * 16 + n15];
#pragma unroll
  for (int c = 0; c < 4; ++c) acc[c] = (f32x4){0.f, 0.f, 0.f, 0.f};
#pragma unroll
  for (int s = 0; s < 4; ++s) {
    short8 a = *(const short8*)&As[abase + s * 32];
#pragma unroll
    for (int c = 0; c < 4; ++c) {
      short8 b = *(const short8*)&Pb[(size_t)(((((ct << 2) | c) << 2) | s) * 64 + lane) * 8];
      acc[c] = __builtin_amdgcn_mfma_f32_16x16x32_bf16(a, b, acc[c], 0, 0, 0);
    }
  }

  // ---- expmap0 epilogue: row norm = this wave's partial + partner via LDS ----
  float v[4][4];
#pragma unroll
  for (int rr = 0; rr < 4; ++rr) {
    float ssq = 0.f;
#pragma unroll
    for (int c = 0; c < 4; ++c) {
      v[c][rr] = acc[c][rr] + bc[c];
      ssq += v[c][rr] * v[c][rr];
    }
    ssq += __shfl_xor(ssq, 1);
    ssq += __shfl_xor(ssq, 2);
    ssq += __shfl_xor(ssq, 4);
    ssq += __shfl_xor(ssq, 8);
    if (n15 == 0) nrmb[(rt * 16 + q * 4 + rr) * 2 + ct] = ssq;
  }
  __syncthreads();
#pragma unroll
  for (int rr = 0; rr < 4; ++rr) {
    int r = rt * 16 + q * 4 + rr;
    int grow = row0 + r;
    float ssq = nrmb[r * 2] + nrmb[r * 2 + 1];
    float nrm = sqrtf(ssq);
    float nc = fmaxf(nrm, 1e-8f);
    float sc = tanhf(nc) / nc;
    if (grow < N) {
#pragma unroll
      for (int c = 0; c < 4; ++c)
        __builtin_nontemporal_store(
            v[c][rr] * sc, out + (size_t)grow * DD + ct * 64 + c * 16 + n15);
    }
  }
}

extern "C" void kernel_launch(void* const* d_in, const int* in_sizes, int n_in,
                              void* d_out, int out_size, void* d_ws, size_t ws_size,
                              hipStream_t stream) {
  const float* x = (const float*)d_in[0];
  const int* ei = (const int*)d_in[1];
  const float* w1 = (const float*)d_in[2];
  const float* b1 = (const float*)d_in[3];
  const float* w2 = (const float*)d_in[4];
  const float* b2 = (const float*)d_in[5];
  const float* w3 = (const float*)d_in[6];
  const float* b3 = (const float*)d_in[7];
  const float* w4 = (const float*)d_in[8];
  const float* b4 = (const float*)d_in[9];
  const int N = in_sizes[0] / DD;
  const int E = in_sizes[1] / 2;
  const int nf = (N + 63) / 64;
  const int ne = (E + 1023) / 1024;  // 2 edges/thread, 1024/block

  // ws carve: node_msg[N*128 bf16] | degv[N] | ebuf[N*64 int] | P[4*16384 bf16]
  unsigned short* node_msg = (unsigned short*)d_ws;
  int* degv = (int*)(node_msg + (size_t)N * DD);
  int* ebuf = degv + N;
  uintptr_t pw = (uintptr_t)(ebuf + (size_t)N * CAP);
  pw = (pw + 63) & ~(uintptr_t)63;
  unsigned short* P = (unsigned short*)pw;
  float* outp = (float*)d_out;

  hipLaunchKernelGGL(k_init, dim3(32 + (N + 255) / 256), dim3(256), 0, stream,
                     w1, w2, w3, w4, P, degv, N);
  hipLaunchKernelGGL(k_stage1, dim3(nf + ne), dim3(512), 0, stream,
                     x, ei, P, b1, P + 16384, b2, node_msg, degv, ebuf, N, E, nf);
  hipLaunchKernelGGL(k_stage2, dim3(nf), dim3(512), 0, stream,
                     node_msg, degv, ebuf, P + 2 * 16384, b3, P + 3 * 16384, b4,
                     outp, N);
}

// Round 9
// 165.090 us; speedup vs baseline: 1.8198x; 1.0246x over previous
//
#include <hip/hip_runtime.h>
#include <hip/hip_bf16.h>

// HyperbolicMessagePassing: N=50000, E=600000, D=128.
// out = expmap0( MLP2( mean_scatter( MLP1(logmap0(x))[src] -> dst ) ) )
// Message MLP depends only on src -> compute per-node (50k rows not 600k).
// R9: R8 base (169us) + 4-edge/thread fill ILP, fill blocks first in grid,
// stage2 fixed-16 sanitized gather window (16 loads in flight per row).

#define DD 128
#define CAP 64  // padded-CSR slots per node

typedef __attribute__((ext_vector_type(8))) short short8;
typedef __attribute__((ext_vector_type(4))) float f32x4;

__device__ __forceinline__ unsigned short f2bf(float f) {
  unsigned u = __float_as_uint(f);
  u += 0x7fffu + ((u >> 16) & 1u);  // round-to-nearest-even
  return (unsigned short)(u >> 16);
}
__device__ __forceinline__ float bf2f(short h) {
  return __uint_as_float(((unsigned)(unsigned short)h) << 16);
}

// blocks [0,32): pack 4 W (fp32 128x128) into bf16 MFMA B-frag-linear order:
//   P[m*16384 + ((cc*4+s)*64 + lane)*8 + j]
//     = bf16(W[(s*32+(lane>>4)*8+j)*128 + cc*16+(lane&15)])
// blocks [32,..): zero degv[N]
__global__ void k_init(const float* __restrict__ w1, const float* __restrict__ w2,
                       const float* __restrict__ w3, const float* __restrict__ w4,
                       unsigned short* __restrict__ P, int* __restrict__ degv, int N) {
  if (blockIdx.x < 32) {
    int idx = blockIdx.x * 256 + threadIdx.x;  // 4 matrices x 2048 (frag,lane)
    int m = idx >> 11;
    int id = idx & 2047;
    int f = id >> 6, l = id & 63;
    int cc = f >> 2, s = f & 3, q = l >> 4, n15 = l & 15;
    const float* W = (m == 0) ? w1 : (m == 1) ? w2 : (m == 2) ? w3 : w4;
    const float* wp = W + (s * 32 + q * 8) * DD + cc * 16 + n15;
    unsigned short* op = P + (size_t)m * 16384 + (size_t)id * 8;
#pragma unroll
    for (int j = 0; j < 8; ++j) op[j] = f2bf(wp[j * DD]);
  } else {
    int i = (blockIdx.x - 32) * 256 + threadIdx.x;
    if (i < N) degv[i] = 0;
  }
}

// stage1: blocks [0,ne) = padded-CSR edge fill, 4 edges/thread (latency-bound
//         -> dispatched FIRST); blocks [ne,..) = logmap0 + MLP1 -> node_msg.
// 512 threads = 8 waves. Wave wv: rt=wv>>1 (16 rows), ct=wv&1 (64 cols).
__global__ __launch_bounds__(512) void k_stage1(
    const float* __restrict__ x, const int* __restrict__ ei,
    const unsigned short* __restrict__ Pa, const float* __restrict__ ba,
    const unsigned short* __restrict__ Pb, const float* __restrict__ bb,
    unsigned short* __restrict__ node_msg, int* __restrict__ degv,
    int* __restrict__ ebuf, int N, int E, int ne) {
  __shared__ unsigned short As[64 * 136];  // row stride 136 shorts
  const int tid = threadIdx.x;

  if (blockIdx.x < ne) {  // ---- edge-fill: 2048 edges/block, 4/thread ----
    int eb_[4], d_[4], s_[4], p_[4];
#pragma unroll
    for (int k = 0; k < 4; ++k) {
      int e = blockIdx.x * 2048 + k * 512 + tid;
      eb_[k] = e;
      if (e < E) {
        d_[k] = ei[e];       // edge_index[0] = row (dst)
        s_[k] = ei[E + e];   // edge_index[1] = col (src)
      }
    }
#pragma unroll
    for (int k = 0; k < 4; ++k)
      if (eb_[k] < E) p_[k] = atomicAdd(degv + d_[k], 1);
#pragma unroll
    for (int k = 0; k < 4; ++k)
      if (eb_[k] < E && p_[k] < CAP) ebuf[(size_t)d_[k] * CAP + p_[k]] = s_[k];
    return;
  }

  const int lane = tid & 63;
  const int wv = tid >> 6;  // 0..7
  const int rt = wv >> 1;   // row-tile 0..3
  const int ct = wv & 1;    // col-tile 0..1
  const int q = lane >> 4;
  const int n15 = lane & 15;
  const int row0 = (blockIdx.x - ne) * 64;
  const int g = (wv << 2) | q;  // staging group 0..31

  // ---- stage A tile: logmap0, group g rows g*2..g*2+1, 16 lanes/row ----
#pragma unroll
  for (int i = 0; i < 2; ++i) {
    const int r = g * 2 + i;
    const int grow = row0 + r;
    f32x4 s0 = {0.f, 0.f, 0.f, 0.f}, s1 = {0.f, 0.f, 0.f, 0.f};
    if (grow < N) {
      const f32x4* p = (const f32x4*)(x + (size_t)grow * DD + n15 * 8);
      s0 = p[0];
      s1 = p[1];
      float ss = s0[0]*s0[0] + s0[1]*s0[1] + s0[2]*s0[2] + s0[3]*s0[3]
               + s1[0]*s1[0] + s1[1]*s1[1] + s1[2]*s1[2] + s1[3]*s1[3];
      ss += __shfl_xor(ss, 1);
      ss += __shfl_xor(ss, 2);
      ss += __shfl_xor(ss, 4);
      ss += __shfl_xor(ss, 8);
      float nrm = sqrtf(ss);
      float nc = fminf(fmaxf(nrm, 1e-8f), 1.0f - 1e-5f);
      float sc = atanhf(nc) / nc;
      s0 *= sc;
      s1 *= sc;
    }
    uint4 pk;
    pk.x = (unsigned)f2bf(s0[0]) | ((unsigned)f2bf(s0[1]) << 16);
    pk.y = (unsigned)f2bf(s0[2]) | ((unsigned)f2bf(s0[3]) << 16);
    pk.z = (unsigned)f2bf(s1[0]) | ((unsigned)f2bf(s1[1]) << 16);
    pk.w = (unsigned)f2bf(s1[2]) | ((unsigned)f2bf(s1[3]) << 16);
    *(uint4*)((unsigned*)As + r * 68 + n15 * 4) = pk;
  }
  __syncthreads();

  // ---- layer 1 ----
  float bc[4];
#pragma unroll
  for (int c = 0; c < 4; ++c) bc[c] = ba[ct * 64 + c * 16 + n15];
  f32x4 acc[4];
#pragma unroll
  for (int c = 0; c < 4; ++c) acc[c] = (f32x4){0.f, 0.f, 0.f, 0.f};
  const int abase = (rt * 16 + n15) * 136 + q * 8;  // A[m=n15][k=q*8+j]
#pragma unroll
  for (int s = 0; s < 4; ++s) {
    short8 a = *(const short8*)&As[abase + s * 32];
#pragma unroll
    for (int c = 0; c < 4; ++c) {
      short8 b = *(const short8*)&Pa[(size_t)(((((ct << 2) | c) << 2) | s) * 64 + lane) * 8];
      acc[c] = __builtin_amdgcn_mfma_f32_16x16x32_bf16(a, b, acc[c], 0, 0, 0);
    }
  }
  __syncthreads();

  // relu + bias -> As (C/D: row = rt*16 + q*4 + rr, col = ct*64 + c*16 + n15)
#pragma unroll
  for (int c = 0; c < 4; ++c)
#pragma unroll
    for (int rr = 0; rr < 4; ++rr) {
      float v = fmaxf(acc[c][rr] + bc[c], 0.f);
      As[(rt * 16 + q * 4 + rr) * 136 + ct * 64 + c * 16 + n15] = f2bf(v);
    }
  __syncthreads();

  // ---- layer 2 ----
#pragma unroll
  for (int c = 0; c < 4; ++c) bc[c] = bb[ct * 64 + c * 16 + n15];
#pragma unroll
  for (int c = 0; c < 4; ++c) acc[c] = (f32x4){0.f, 0.f, 0.f, 0.f};
#pragma unroll
  for (int s = 0; s < 4; ++s) {
    short8 a = *(const short8*)&As[abase + s * 32];
#pragma unroll
    for (int c = 0; c < 4; ++c) {
      short8 b = *(const short8*)&Pb[(size_t)(((((ct << 2) | c) << 2) | s) * 64 + lane) * 8];
      acc[c] = __builtin_amdgcn_mfma_f32_16x16x32_bf16(a, b, acc[c], 0, 0, 0);
    }
  }

  // write bf16 node_msg via LDS repack -> coalesced 16B stores
  __syncthreads();
#pragma unroll
  for (int c = 0; c < 4; ++c)
#pragma unroll
    for (int rr = 0; rr < 4; ++rr)
      As[(rt * 16 + q * 4 + rr) * 136 + ct * 64 + c * 16 + n15] =
          f2bf(acc[c][rr] + bc[c]);
  __syncthreads();
#pragma unroll
  for (int k = 0; k < 2; ++k) {  // 64 rows x 16 chunks = 1024 units / 512 thr
    int u = tid + k * 512;
    int r = u >> 4, ch = u & 15;
    int grow = row0 + r;
    if (grow < N)
      *(short8*)(node_msg + (size_t)grow * DD + ch * 8) =
          *(const short8*)&As[r * 136 + ch * 8];
  }
}

// stage2: padded-CSR gather + mean -> 2-layer MLP -> expmap0 -> out (f32)
__global__ __launch_bounds__(512) void k_stage2(
    const unsigned short* __restrict__ node_msg, const int* __restrict__ degv,
    const int* __restrict__ ebuf, const unsigned short* __restrict__ Pa,
    const float* __restrict__ ba, const unsigned short* __restrict__ Pb,
    const float* __restrict__ bb, float* __restrict__ out, int N) {
  __shared__ unsigned short As[64 * 136];
  __shared__ float nrmb[128];  // [row][ct] partial norms
  const int tid = threadIdx.x;
  const int lane = tid & 63;
  const int wv = tid >> 6;
  const int rt = wv >> 1;
  const int ct = wv & 1;
  const int q = lane >> 4;
  const int n15 = lane & 15;
  const int row0 = blockIdx.x * 64;
  const int g = (wv << 2) | q;

  // hoist deg loads for both of this group's rows
  int dpre[2];
#pragma unroll
  for (int i = 0; i < 2; ++i) {
    int grow = row0 + g * 2 + i;
    dpre[i] = (grow < N) ? degv[grow] : 0;
  }

  // ---- gather + mean: fixed 16-slot window, sanitized indices ----
  // All 16 row-gathers issued independently (poison slots -> index 0, adds
  // predicated on t<dl which is uniform across the 16-lane group).
#pragma unroll
  for (int i = 0; i < 2; ++i) {
    const int r = g * 2 + i;
    const int grow = row0 + r;
    f32x4 s0 = {0.f, 0.f, 0.f, 0.f}, s1 = {0.f, 0.f, 0.f, 0.f};
    if (grow < N) {
      const int d = dpre[i];
      const int dl = (d < CAP) ? d : CAP;
      const int* eb = ebuf + (size_t)grow * CAP;
      int4 cA = *(const int4*)(eb);
      int4 cB = *(const int4*)(eb + 4);
      int4 cC = *(const int4*)(eb + 8);
      int4 cD = *(const int4*)(eb + 12);
      int id[16] = {cA.x, cA.y, cA.z, cA.w, cB.x, cB.y, cB.z, cB.w,
                    cC.x, cC.y, cC.z, cC.w, cD.x, cD.y, cD.z, cD.w};
      short8 v[16];
#pragma unroll
      for (int t = 0; t < 16; ++t) {
        int sidx = (t < dl) ? id[t] : 0;  // clamp poison to a safe hot row
        v[t] = *(const short8*)(node_msg + (size_t)sidx * DD + n15 * 8);
      }
      f32x4 t0 = {0.f, 0.f, 0.f, 0.f}, t1 = {0.f, 0.f, 0.f, 0.f};
#pragma unroll
      for (int t = 0; t < 16; ++t) {
        if (t < dl) {
#pragma unroll
          for (int j = 0; j < 4; ++j) {
            if (t & 1) {
              t0[j] += bf2f(v[t][j]);
              t1[j] += bf2f(v[t][j + 4]);
            } else {
              s0[j] += bf2f(v[t][j]);
              s1[j] += bf2f(v[t][j + 4]);
            }
          }
        }
      }
      // tail: deg > 16 (~10% of rows), 4-deep
      int t = 16;
      for (; t + 3 < dl; t += 4) {
        int4 idx = *(const int4*)(eb + t);
        short8 v0 = *(const short8*)(node_msg + (size_t)idx.x * DD + n15 * 8);
        short8 v1 = *(const short8*)(node_msg + (size_t)idx.y * DD + n15 * 8);
        short8 v2 = *(const short8*)(node_msg + (size_t)idx.z * DD + n15 * 8);
        short8 v3 = *(const short8*)(node_msg + (size_t)idx.w * DD + n15 * 8);
#pragma unroll
        for (int j = 0; j < 4; ++j) {
          s0[j] += bf2f(v0[j]) + bf2f(v1[j]);
          s1[j] += bf2f(v0[j + 4]) + bf2f(v1[j + 4]);
          t0[j] += bf2f(v2[j]) + bf2f(v3[j]);
          t1[j] += bf2f(v2[j + 4]) + bf2f(v3[j + 4]);
        }
      }
      for (; t < dl; ++t) {
        int sa = eb[t];
        short8 va = *(const short8*)(node_msg + (size_t)sa * DD + n15 * 8);
#pragma unroll
        for (int j = 0; j < 4; ++j) {
          s0[j] += bf2f(va[j]);
          s1[j] += bf2f(va[j + 4]);
        }
      }
      s0 += t0;
      s1 += t1;
      float inv = 1.f / ((float)d + 1e-8f);  // mean (count + EPS)
      s0 *= inv;
      s1 *= inv;
    }
    uint4 pk;
    pk.x = (unsigned)f2bf(s0[0]) | ((unsigned)f2bf(s0[1]) << 16);
    pk.y = (unsigned)f2bf(s0[2]) | ((unsigned)f2bf(s0[3]) << 16);
    pk.z = (unsigned)f2bf(s1[0]) | ((unsigned)f2bf(s1[1]) << 16);
    pk.w = (unsigned)f2bf(s1[2]) | ((unsigned)f2bf(s1[3]) << 16);
    *(uint4*)((unsigned*)As + r * 68 + n15 * 4) = pk;
  }
  __syncthreads();

  // ---- layer 1 ----
  float bc[4];
#pragma unroll
  for (int c = 0; c < 4; ++c) bc[c] = ba[ct * 64 + c * 16 + n15];
  f32x4 acc[4];
#pragma unroll
  for (int c = 0; c < 4; ++c) acc[c] = (f32x4){0.f, 0.f, 0.f, 0.f};
  const int abase = (rt * 16 + n15) * 136 + q * 8;
#pragma unroll
  for (int s = 0; s < 4; ++s) {
    short8 a = *(const short8*)&As[abase + s * 32];
#pragma unroll
    for (int c = 0; c < 4; ++c) {
      short8 b = *(const short8*)&Pa[(size_t)(((((ct << 2) | c) << 2) | s) * 64 + lane) * 8];
      acc[c] = __builtin_amdgcn_mfma_f32_16x16x32_bf16(a, b, acc[c], 0, 0, 0);
    }
  }
  __syncthreads();

#pragma unroll
  for (int c = 0; c < 4; ++c)
#pragma unroll
    for (int rr = 0; rr < 4; ++rr) {
      float v = fmaxf(acc[c][rr] + bc[c], 0.f);
      As[(rt * 16 + q * 4 + rr) * 136 + ct * 64 + c * 16 + n15] = f2bf(v);
    }
  __syncthreads();

  // ---- layer 2 ----
#pragma unroll
  for (int c = 0; c < 4; ++c) bc[c] = bb[ct * 64 + c * 16 + n15];
#pragma unroll
  for (int c = 0; c < 4; ++c) acc[c] = (f32x4){0.f, 0.f, 0.f, 0.f};
#pragma unroll
  for (int s = 0; s < 4; ++s) {
    short8 a = *(const short8*)&As[abase + s * 32];
#pragma unroll
    for (int c = 0; c < 4; ++c) {
      short8 b = *(const short8*)&Pb[(size_t)(((((ct << 2) | c) << 2) | s) * 64 + lane) * 8];
      acc[c] = __builtin_amdgcn_mfma_f32_16x16x32_bf16(a, b, acc[c], 0, 0, 0);
    }
  }

  // ---- expmap0 epilogue ----
  float v[4][4];
#pragma unroll
  for (int rr = 0; rr < 4; ++rr) {
    float ssq = 0.f;
#pragma unroll
    for (int c = 0; c < 4; ++c) {
      v[c][rr] = acc[c][rr] + bc[c];
      ssq += v[c][rr] * v[c][rr];
    }
    ssq += __shfl_xor(ssq, 1);
    ssq += __shfl_xor(ssq, 2);
    ssq += __shfl_xor(ssq, 4);
    ssq += __shfl_xor(ssq, 8);
    if (n15 == 0) nrmb[(rt * 16 + q * 4 + rr) * 2 + ct] = ssq;
  }
  __syncthreads();
#pragma unroll
  for (int rr = 0; rr < 4; ++rr) {
    int r = rt * 16 + q * 4 + rr;
    int grow = row0 + r;
    float ssq = nrmb[r * 2] + nrmb[r * 2 + 1];
    float nrm = sqrtf(ssq);
    float nc = fmaxf(nrm, 1e-8f);
    float sc = tanhf(nc) / nc;
    if (grow < N) {
#pragma unroll
      for (int c = 0; c < 4; ++c)
        __builtin_nontemporal_store(
            v[c][rr] * sc, out + (size_t)grow * DD + ct * 64 + c * 16 + n15);
    }
  }
}

extern "C" void kernel_launch(void* const* d_in, const int* in_sizes, int n_in,
                              void* d_out, int out_size, void* d_ws, size_t ws_size,
                              hipStream_t stream) {
  const float* x = (const float*)d_in[0];
  const int* ei = (const int*)d_in[1];
  const float* w1 = (const float*)d_in[2];
  const float* b1 = (const float*)d_in[3];
  const float* w2 = (const float*)d_in[4];
  const float* b2 = (const float*)d_in[5];
  const float* w3 = (const float*)d_in[6];
  const float* b3 = (const float*)d_in[7];
  const float* w4 = (const float*)d_in[8];
  const float* b4 = (const float*)d_in[9];
  const int N = in_sizes[0] / DD;
  const int E = in_sizes[1] / 2;
  const int nf = (N + 63) / 64;
  const int ne = (E + 2047) / 2048;  // 4 edges/thread, 2048/block

  // ws carve: node_msg[N*128 bf16] | degv[N] | ebuf[N*64 int] | P[4*16384 bf16]
  unsigned short* node_msg = (unsigned short*)d_ws;
  int* degv = (int*)(node_msg + (size_t)N * DD);
  int* ebuf = degv + N;
  uintptr_t pw = (uintptr_t)(ebuf + (size_t)N * CAP);
  pw = (pw + 63) & ~(uintptr_t)63;
  unsigned short* P = (unsigned short*)pw;
  float* outp = (float*)d_out;

  hipLaunchKernelGGL(k_init, dim3(32 + (N + 255) / 256), dim3(256), 0, stream,
                     w1, w2, w3, w4, P, degv, N);
  hipLaunchKernelGGL(k_stage1, dim3(ne + nf), dim3(512), 0, stream,
                     x, ei, P, b1, P + 16384, b2, node_msg, degv, ebuf, N, E, ne);
  hipLaunchKernelGGL(k_stage2, dim3(nf), dim3(512), 0, stream,
                     node_msg, degv, ebuf, P + 2 * 16384, b3, P + 3 * 16384, b4,
                     outp, N);
}